// Round 1
// baseline (885.103 us; speedup 1.0000x reference)
//
#include <hip/hip_runtime.h>
#include <hip/hip_bf16.h>
#include <math.h>

#define N_B 32
#define T_S 512
#define D_D 1024
#define C_C 120
#define SCALE 64.0f  // 2*sqrt(1024)

typedef unsigned short u16;
typedef __attribute__((ext_vector_type(8))) short short8;
typedef __attribute__((ext_vector_type(4))) float floatx4;

__device__ inline u16 f2bf(float f) {
    union { __hip_bfloat16 h; u16 u; } c; c.h = __float2bfloat16(f); return c.u;
}

// ---- mask dtype robustness: harness may deliver bool as int32 or int8 ----
__device__ inline bool mask_is_i8(const int* mk) {
    bool i8 = false;
#pragma unroll
    for (int i = 0; i < 16; i++) {
        unsigned v = ((const unsigned*)mk)[i];
        if (v > 1u) i8 = true;
    }
    return i8;
}
__device__ inline int mask_val(const int* mk, int idx, bool i8) {
    return i8 ? (int)((const signed char*)mk)[idx] : mk[idx];
}

// ---- 1024x1024 fp32 transpose ----
__global__ void k_tr_f32(const float* __restrict__ in, float* __restrict__ out) {
    __shared__ float tile[32][33];
    int bx = blockIdx.x, by = blockIdx.y;
    int tx = threadIdx.x, ty = threadIdx.y;
#pragma unroll
    for (int j = 0; j < 32; j += 8)
        tile[ty + j][tx] = in[(size_t)(by*32 + ty + j)*D_D + bx*32 + tx];
    __syncthreads();
#pragma unroll
    for (int j = 0; j < 32; j += 8)
        out[(size_t)(bx*32 + ty + j)*D_D + by*32 + tx] = tile[tx][ty + j];
}

// ---- 1024x1024 transpose + fp32->bf16 ----
__global__ void k_tr_bf16(const float* __restrict__ in, u16* __restrict__ out) {
    __shared__ float tile[32][33];
    int bx = blockIdx.x, by = blockIdx.y;
    int tx = threadIdx.x, ty = threadIdx.y;
#pragma unroll
    for (int j = 0; j < 32; j += 8)
        tile[ty + j][tx] = in[(size_t)(by*32 + ty + j)*D_D + bx*32 + tx];
    __syncthreads();
#pragma unroll
    for (int j = 0; j < 32; j += 8)
        out[(size_t)(bx*32 + ty + j)*D_D + by*32 + tx] = f2bf(tile[tx][ty + j]);
}

// ---- masked column-sum of x over valid t, plus valid count ----
__global__ void k_xsum(const float* x0, const float* x1, const float* x2,
                       const int* m0, const int* m1, const int* m2,
                       float* __restrict__ xsum, int* __restrict__ nvalid) {
    int z = blockIdx.z, b = blockIdx.y, tc = blockIdx.x;
    const float* x = z == 0 ? x0 : (z == 1 ? x1 : x2);
    const int* mk = z == 0 ? m0 : (z == 1 ? m1 : m2);
    bool i8 = mask_is_i8(mk);
    int tid = threadIdx.x;
    int t0 = tc * 64;
    const float4* xr = (const float4*)(x + (size_t)(b * T_S) * D_D);
    float4 acc = {0.f, 0.f, 0.f, 0.f};
    for (int i = 0; i < 64; i++) {
        int t = t0 + i;
        if (mask_val(mk, b * T_S + t, i8) == 0) {   // uniform branch: skip padded rows
            float4 v = xr[(size_t)t * 256 + tid];
            acc.x += v.x; acc.y += v.y; acc.z += v.z; acc.w += v.w;
        }
    }
    float* xs = xsum + (size_t)(z * N_B + b) * D_D + tid * 4;
    atomicAdd(xs + 0, acc.x); atomicAdd(xs + 1, acc.y);
    atomicAdd(xs + 2, acc.z); atomicAdd(xs + 3, acc.w);
    if (tid < 64) {
        bool valid = (mask_val(mk, b * T_S + t0 + tid, i8) == 0);
        unsigned long long bal = __ballot(valid);
        if (tid == 0) atomicAdd(&nvalid[z * N_B + b], (int)__popcll(bal));
    }
}

// ---- generic batched (4 rows/block) vec@W: out[b][o] = sum_i vin[b][i]*W[i][o] ----
// bias optional; bmul optional (per-row int multiplier on bias); scale on output
__global__ void k_matvec(const float* __restrict__ W, const float* __restrict__ vin,
                         const float* __restrict__ bias, const int* __restrict__ bmul,
                         float scale, float* __restrict__ vout) {
    int z = blockIdx.z, bg = blockIdx.y;
    int o = blockIdx.x * 256 + threadIdx.x;
    int brow = z * N_B + bg * 4;
    float bv = bias ? bias[o] : 0.0f;
    float acc[4];
#pragma unroll
    for (int bb = 0; bb < 4; bb++)
        acc[bb] = bias ? (bmul ? bv * (float)bmul[brow + bb] : bv) : 0.0f;
    const float* vi = vin + (size_t)brow * D_D;
#pragma unroll 4
    for (int i = 0; i < D_D; i++) {
        float wv = W[(size_t)i * D_D + o];
#pragma unroll
        for (int bb = 0; bb < 4; bb++)
            acc[bb] += vi[(size_t)bb * D_D + i] * wv;
    }
#pragma unroll
    for (int bb = 0; bb < 4; bb++)
        vout[(size_t)(brow + bb) * D_D + o] = acc[bb] * scale;
}

// ---- s[b,t] = x[b,t,:] . vs[b,:]  (vs already has 1/SCALE folded in) ----
__global__ void k_dots(const float* x0, const float* x1, const float* x2,
                       const float* __restrict__ vs, float* __restrict__ sdot) {
    int z = blockIdx.z, b = blockIdx.y;
    const float* x = z == 0 ? x0 : (z == 1 ? x1 : x2);
    int t = blockIdx.x * 4 + (threadIdx.x >> 6);
    int lane = threadIdx.x & 63;
    const float4* xr = (const float4*)(x + (size_t)(b * T_S + t) * D_D);
    const float4* vr = (const float4*)(vs + (size_t)(z * N_B + b) * D_D);
    float acc = 0.f;
#pragma unroll
    for (int i = 0; i < 4; i++) {
        float4 xv = xr[i * 64 + lane];
        float4 vv = vr[i * 64 + lane];
        acc += xv.x * vv.x + xv.y * vv.y + xv.z * vv.z + xv.w * vv.w;
    }
#pragma unroll
    for (int off = 32; off; off >>= 1) acc += __shfl_xor(acc, off, 64);
    if (lane == 0) sdot[(size_t)(z * N_B + b) * T_S + t] = acc;
}

// ---- masked softmax over t (one block per (b,z), 512 threads) ----
__global__ void k_softmax(const float* __restrict__ sdot,
                          const int* m0, const int* m1, const int* m2,
                          float* __restrict__ attn) {
    int b = blockIdx.x, z = blockIdx.y;
    const int* mk = z == 0 ? m0 : (z == 1 ? m1 : m2);
    bool i8 = mask_is_i8(mk);
    int t = threadIdx.x;
    int base = (z * N_B + b) * T_S;
    float sval = sdot[base + t];
    if (mask_val(mk, b * T_S + t, i8) != 0) sval = -INFINITY;
    float m = sval;
#pragma unroll
    for (int off = 32; off; off >>= 1) m = fmaxf(m, __shfl_xor(m, off, 64));
    __shared__ float redm[8], reds[8];
    int w = t >> 6;
    if ((t & 63) == 0) redm[w] = m;
    __syncthreads();
    float mx = redm[0];
#pragma unroll
    for (int k = 1; k < 8; k++) mx = fmaxf(mx, redm[k]);
    float e = __expf(sval - mx);
    float ssum = e;
#pragma unroll
    for (int off = 32; off; off >>= 1) ssum += __shfl_xor(ssum, off, 64);
    if ((t & 63) == 0) reds[w] = ssum;
    __syncthreads();
    float tot = 0.f;
#pragma unroll
    for (int k = 0; k < 8; k++) tot += reds[k];
    attn[base + t] = e / tot;
}

// ---- big fused GEMM: h = x@W1 (+b1, relu, *attn, row-reduce -> r) ----
// 128x128 tile, BK=64, bf16 16x16x32 MFMA. A staged fp32->bf16 via VGPRs,
// B (pre-transposed bf16 W1T) staged via vector loads. LDS rows padded to
// 144B (2-way bank aliasing on frag reads = free).
__global__ __launch_bounds__(256, 3)
void k_gemm(const float* x0, const float* x1, const float* x2,
            const u16* __restrict__ W1T, const float* __restrict__ b1,
            const float* __restrict__ attn, float* __restrict__ r) {
    int z = blockIdx.z;
    const float* x = z == 0 ? x0 : (z == 1 ? x1 : x2);
    int tid = threadIdx.x;
    int row0 = blockIdx.y * 128;
    int N0 = blockIdx.x * 128;
    int b = row0 >> 9;

    __shared__ __align__(16) u16 As[128 * 72];
    __shared__ __align__(16) u16 Bs[128 * 72];
    __shared__ float sAttn[128];
    if (tid < 128) sAttn[tid] = attn[(size_t)(z * N_B + b) * T_S + (row0 & 511) + tid];

    int wave = tid >> 6, lane = tid & 63;
    int wy = wave >> 1, wx = wave & 1;
    int q = lane >> 4, cidx = lane & 15;

    floatx4 acc[4][4];
#pragma unroll
    for (int mi = 0; mi < 4; mi++)
#pragma unroll
        for (int ni = 0; ni < 4; ni++)
            acc[mi][ni] = (floatx4){0.f, 0.f, 0.f, 0.f};

    const float* aptr = x + (size_t)row0 * D_D;
    int acol = (tid & 15) * 4;            // fp32 col within BK
    int bchunk = (tid & 7) * 8;           // bf16 col within BK
    const u16* bptr = W1T + (size_t)N0 * D_D;

    for (int k0 = 0; k0 < 1024; k0 += 64) {
        __syncthreads();
        // A: 128 rows x 64 cols fp32 -> bf16 into LDS
#pragma unroll
        for (int p = 0; p < 8; p++) {
            int rr = p * 16 + (tid >> 4);
            float4 v = *(const float4*)(aptr + (size_t)rr * D_D + k0 + acol);
            union { __hip_bfloat162 h; ushort2 u; } c0, c1;
            c0.h = __float22bfloat162_rn({v.x, v.y});
            c1.h = __float22bfloat162_rn({v.z, v.w});
            ushort4 uu = {c0.u.x, c0.u.y, c1.u.x, c1.u.y};
            *(ushort4*)&As[rr * 72 + acol] = uu;
        }
        // B: 128 n-rows x 64 k (bf16, already transposed)
#pragma unroll
        for (int p = 0; p < 4; p++) {
            int nn = p * 32 + (tid >> 3);
            short8 wv = *(const short8*)(bptr + (size_t)nn * D_D + k0 + bchunk);
            *(short8*)&Bs[nn * 72 + bchunk] = wv;
        }
        __syncthreads();
#pragma unroll
        for (int ks = 0; ks < 2; ks++) {
            short8 a[4], bf[4];
#pragma unroll
            for (int mi = 0; mi < 4; mi++) {
                int m = wy * 64 + mi * 16 + cidx;
                a[mi] = *(const short8*)&As[m * 72 + ks * 32 + q * 8];
            }
#pragma unroll
            for (int ni = 0; ni < 4; ni++) {
                int n = wx * 64 + ni * 16 + cidx;
                bf[ni] = *(const short8*)&Bs[n * 72 + ks * 32 + q * 8];
            }
#pragma unroll
            for (int mi = 0; mi < 4; mi++)
#pragma unroll
                for (int ni = 0; ni < 4; ni++)
                    acc[mi][ni] = __builtin_amdgcn_mfma_f32_16x16x32_bf16(
                        a[mi], bf[ni], acc[mi][ni], 0, 0, 0);
        }
    }

    // epilogue: relu(h + b1) * attn[row], reduce over rows, atomicAdd into r
    float* rrow = r + (size_t)(z * N_B + b) * D_D;
#pragma unroll
    for (int ni = 0; ni < 4; ni++) {
        int ng = N0 + wx * 64 + ni * 16 + cidx;
        float b1v = b1[ng];
        float sum = 0.f;
#pragma unroll
        for (int mi = 0; mi < 4; mi++) {
#pragma unroll
            for (int rg = 0; rg < 4; rg++) {
                int ml = wy * 64 + mi * 16 + q * 4 + rg;
                float hv = acc[mi][ni][rg] + b1v;
                hv = fmaxf(hv, 0.f);
                sum += hv * sAttn[ml];
            }
        }
        sum += __shfl_xor(sum, 16, 64);
        sum += __shfl_xor(sum, 32, 64);
        if (lane < 16) atomicAdd(&rrow[ng], sum);
    }
}

// ---- LayerNorm + relu + final (32x1024)@(1024x120) classifier ----
__global__ void k_out(const float* __restrict__ pooled, const float* __restrict__ ln_g,
                      const float* __restrict__ ln_b, const float* __restrict__ Wl,
                      const float* __restrict__ bl, float* __restrict__ out) {
    int b = blockIdx.x, z = blockIdx.y;
    int tid = threadIdx.x;  // 128
    const float* p = pooled + (size_t)(z * N_B + b) * D_D;
    __shared__ float nr[D_D];
    __shared__ float redA[2], redB[2];
    float vals[8];
    float s1 = 0.f, s2 = 0.f;
#pragma unroll
    for (int i = 0; i < 8; i++) {
        float v = p[i * 128 + tid];
        vals[i] = v; s1 += v; s2 += v * v;
    }
#pragma unroll
    for (int off = 32; off; off >>= 1) {
        s1 += __shfl_xor(s1, off, 64);
        s2 += __shfl_xor(s2, off, 64);
    }
    int w = tid >> 6;
    if ((tid & 63) == 0) { redA[w] = s1; redB[w] = s2; }
    __syncthreads();
    float mu = (redA[0] + redA[1]) * (1.0f / D_D);
    float var = (redB[0] + redB[1]) * (1.0f / D_D) - mu * mu;
    float rstd = 1.0f / sqrtf(var + 1e-12f);
#pragma unroll
    for (int i = 0; i < 8; i++) {
        int d = i * 128 + tid;
        float nv = (vals[i] - mu) * rstd * ln_g[d] + ln_b[d];
        nr[d] = fmaxf(nv, 0.f);
    }
    __syncthreads();
    if (tid < C_C) {
        float acc = bl[tid];
#pragma unroll 8
        for (int d = 0; d < D_D; d++)
            acc += nr[d] * Wl[d * C_C + tid];
        out[(size_t)(z * N_B + b) * C_C + tid] = acc;
    }
}

extern "C" void kernel_launch(void* const* d_in, const int* in_sizes, int n_in,
                              void* d_out, int out_size, void* d_ws, size_t ws_size,
                              hipStream_t stream) {
    const float* x0 = (const float*)d_in[0];
    const float* x1 = (const float*)d_in[1];
    const float* x2 = (const float*)d_in[2];
    const int* m0 = (const int*)d_in[3];
    const int* m1 = (const int*)d_in[4];
    const int* m2 = (const int*)d_in[5];
    const float* W_attn = (const float*)d_in[6];
    const float* b_attn = (const float*)d_in[7];
    const float* W1 = (const float*)d_in[8];
    const float* b1 = (const float*)d_in[9];
    const float* W2 = (const float*)d_in[10];
    const float* b2 = (const float*)d_in[11];
    const float* ln_g = (const float*)d_in[12];
    const float* ln_b = (const float*)d_in[13];
    const float* W_last = (const float*)d_in[14];
    const float* b_last = (const float*)d_in[15];
    float* out = (float*)d_out;

    char* wsb = (char*)d_ws;
    float* WT     = (float*)(wsb + 0);                        // 4 MB
    u16*   W1T    = (u16*)  (wsb + (4 << 20));                // 2 MB
    float* xsum   = (float*)(wsb + (6 << 20));                // 384 KB  (zeroed)
    float* rbuf   = (float*)(wsb + (6 << 20) + 393216);       // 384 KB  (zeroed)
    int*   nvalid = (int*)  (wsb + (6 << 20) + 786432);       // 384 B   (zeroed)
    float* wsum   = (float*)(wsb + (8 << 20));                // 384 KB
    float* vs     = (float*)(wsb + (8 << 20) + 393216);       // 384 KB
    float* sdot   = (float*)(wsb + (8 << 20) + 786432);       // 192 KB
    float* attn   = (float*)(wsb + (8 << 20) + 983040);       // 192 KB
    float* pooled = (float*)(wsb + (8 << 20) + 1179648);      // 384 KB

    hipMemsetAsync(wsb + (6 << 20), 0, 1 << 20, stream);

    k_tr_f32 <<<dim3(32, 32), dim3(32, 8), 0, stream>>>(W_attn, WT);
    k_tr_bf16<<<dim3(32, 32), dim3(32, 8), 0, stream>>>(W1, W1T);
    k_xsum   <<<dim3(8, 32, 3), 256, 0, stream>>>(x0, x1, x2, m0, m1, m2, xsum, nvalid);
    // wsum = xsum@W_attn + nvalid*b_attn
    k_matvec <<<dim3(4, 8, 3), 256, 0, stream>>>(W_attn, xsum, b_attn, nvalid, 1.0f, wsum);
    // vs = (W_attn . wsum)/SCALE  via transposed weights
    k_matvec <<<dim3(4, 8, 3), 256, 0, stream>>>(WT, wsum, nullptr, nullptr, 1.0f / SCALE, vs);
    k_dots   <<<dim3(128, 32, 3), 256, 0, stream>>>(x0, x1, x2, vs, sdot);
    k_softmax<<<dim3(32, 3), 512, 0, stream>>>(sdot, m0, m1, m2, attn);
    k_gemm   <<<dim3(8, 128, 3), 256, 0, stream>>>(x0, x1, x2, W1T, b1, attn, rbuf);
    // pooled = r@W2 + b2
    k_matvec <<<dim3(4, 8, 3), 256, 0, stream>>>(W2, rbuf, b2, nullptr, 1.0f, pooled);
    k_out    <<<dim3(32, 3), 128, 0, stream>>>(pooled, ln_g, ln_b, W_last, b_last, out);
}

// Round 2
// 520.556 us; speedup vs baseline: 1.7003x; 1.7003x over previous
//
#include <hip/hip_runtime.h>
#include <hip/hip_bf16.h>
#include <math.h>

#define N_B 32
#define T_S 512
#define D_D 1024
#define C_C 120
#define SCALE 64.0f  // 2*sqrt(1024)

typedef unsigned short u16;
typedef __attribute__((ext_vector_type(8))) short short8;
typedef __attribute__((ext_vector_type(4))) float floatx4;

__device__ inline u16 f2bf(float f) {
    union { __hip_bfloat16 h; u16 u; } c; c.h = __float2bfloat16(f); return c.u;
}

// async global->LDS, 16B per lane. LDS dest = wave-uniform base + lane*16.
__device__ inline void gll16(const void* g, void* l) {
    __builtin_amdgcn_global_load_lds((const __attribute__((address_space(1))) void*)g,
                                     (__attribute__((address_space(3))) void*)l,
                                     16, 0, 0);
}

// ---- mask dtype robustness: harness may deliver bool as int32 or int8 ----
__device__ inline bool mask_is_i8(const int* mk) {
    bool i8 = false;
#pragma unroll
    for (int i = 0; i < 16; i++) {
        unsigned v = ((const unsigned*)mk)[i];
        if (v > 1u) i8 = true;
    }
    return i8;
}
__device__ inline int mask_val(const int* mk, int idx, bool i8) {
    return i8 ? (int)((const signed char*)mk)[idx] : mk[idx];
}

// ---- 1024x1024 fp32 transpose ----
__global__ void k_tr_f32(const float* __restrict__ in, float* __restrict__ out) {
    __shared__ float tile[32][33];
    int bx = blockIdx.x, by = blockIdx.y;
    int tx = threadIdx.x, ty = threadIdx.y;
#pragma unroll
    for (int j = 0; j < 32; j += 8)
        tile[ty + j][tx] = in[(size_t)(by*32 + ty + j)*D_D + bx*32 + tx];
    __syncthreads();
#pragma unroll
    for (int j = 0; j < 32; j += 8)
        out[(size_t)(bx*32 + ty + j)*D_D + by*32 + tx] = tile[tx][ty + j];
}

// ---- 1024x1024 transpose + fp32->bf16 ----
__global__ void k_tr_bf16(const float* __restrict__ in, u16* __restrict__ out) {
    __shared__ float tile[32][33];
    int bx = blockIdx.x, by = blockIdx.y;
    int tx = threadIdx.x, ty = threadIdx.y;
#pragma unroll
    for (int j = 0; j < 32; j += 8)
        tile[ty + j][tx] = in[(size_t)(by*32 + ty + j)*D_D + bx*32 + tx];
    __syncthreads();
#pragma unroll
    for (int j = 0; j < 32; j += 8)
        out[(size_t)(bx*32 + ty + j)*D_D + by*32 + tx] = f2bf(tile[tx][ty + j]);
}

// ---- masked column-sum of x over valid t + valid count + (optional) bf16 copy ----
__global__ void k_xsum(const float* x0, const float* x1, const float* x2,
                       const int* m0, const int* m1, const int* m2,
                       float* __restrict__ xsum, int* __restrict__ nvalid,
                       u16* __restrict__ xb) {
    int z = blockIdx.z, b = blockIdx.y, tc = blockIdx.x;
    const float* x = z == 0 ? x0 : (z == 1 ? x1 : x2);
    const int* mk = z == 0 ? m0 : (z == 1 ? m1 : m2);
    bool i8 = mask_is_i8(mk);
    int tid = threadIdx.x;
    int t0 = tc * 64;
    const float4* xr = (const float4*)(x + (size_t)(b * T_S) * D_D);
    float4 acc = {0.f, 0.f, 0.f, 0.f};
#pragma unroll 4
    for (int i = 0; i < 64; i++) {
        int t = t0 + i;
        float4 v = xr[(size_t)t * 256 + tid];
        if (xb) {
            union { __hip_bfloat162 h; ushort2 u; } c0, c1;
            c0.h = __float22bfloat162_rn({v.x, v.y});
            c1.h = __float22bfloat162_rn({v.z, v.w});
            ushort4 uu = {c0.u.x, c0.u.y, c1.u.x, c1.u.y};
            *(ushort4*)(xb + ((size_t)(z * N_B + b) * T_S + t) * D_D + tid * 4) = uu;
        }
        float sel = (mask_val(mk, b * T_S + t, i8) == 0) ? 1.0f : 0.0f;
        acc.x += v.x * sel; acc.y += v.y * sel;
        acc.z += v.z * sel; acc.w += v.w * sel;
    }
    float* xs = xsum + (size_t)(z * N_B + b) * D_D + tid * 4;
    atomicAdd(xs + 0, acc.x); atomicAdd(xs + 1, acc.y);
    atomicAdd(xs + 2, acc.z); atomicAdd(xs + 3, acc.w);
    if (tid < 64) {
        bool valid = (mask_val(mk, b * T_S + t0 + tid, i8) == 0);
        unsigned long long bal = __ballot(valid);
        if (tid == 0) atomicAdd(&nvalid[z * N_B + b], (int)__popcll(bal));
    }
}

// ---- k-split batched (4 rows/block) vec@W, atomicAdd into zeroed vout ----
__global__ void k_matvec(const float* __restrict__ W, const float* __restrict__ vin,
                         const float* __restrict__ bias, const int* __restrict__ bmul,
                         float scale, float* __restrict__ vout) {
    int z = blockIdx.z, bg = blockIdx.y;
    int och = blockIdx.x >> 2, kc = blockIdx.x & 3;
    int o = och * 256 + threadIdx.x;
    int brow = z * N_B + bg * 4;
    float acc[4] = {0.f, 0.f, 0.f, 0.f};
    if (kc == 0 && bias) {
        float bv = bias[o];
#pragma unroll
        for (int bb = 0; bb < 4; bb++)
            acc[bb] = bmul ? bv * (float)bmul[brow + bb] : bv;
    }
    const float* vi = vin + (size_t)brow * D_D + kc * 256;
    const float* Wp = W + (size_t)(kc * 256) * D_D + o;
#pragma unroll 4
    for (int i = 0; i < 256; i++) {
        float wv = Wp[(size_t)i * D_D];
#pragma unroll
        for (int bb = 0; bb < 4; bb++)
            acc[bb] += vi[(size_t)bb * D_D + i] * wv;
    }
#pragma unroll
    for (int bb = 0; bb < 4; bb++)
        atomicAdd(&vout[(size_t)(brow + bb) * D_D + o], acc[bb] * scale);
}

// ---- s[b,t] = x[b,t,:] . vs[b,:]  (vs already has 1/SCALE folded in) ----
__global__ void k_dots(const float* x0, const float* x1, const float* x2,
                       const float* __restrict__ vs, float* __restrict__ sdot) {
    int z = blockIdx.z, b = blockIdx.y;
    const float* x = z == 0 ? x0 : (z == 1 ? x1 : x2);
    int t = blockIdx.x * 4 + (threadIdx.x >> 6);
    int lane = threadIdx.x & 63;
    const float4* xr = (const float4*)(x + (size_t)(b * T_S + t) * D_D);
    const float4* vr = (const float4*)(vs + (size_t)(z * N_B + b) * D_D);
    float acc = 0.f;
#pragma unroll
    for (int i = 0; i < 4; i++) {
        float4 xv = xr[i * 64 + lane];
        float4 vv = vr[i * 64 + lane];
        acc += xv.x * vv.x + xv.y * vv.y + xv.z * vv.z + xv.w * vv.w;
    }
#pragma unroll
    for (int off = 32; off; off >>= 1) acc += __shfl_xor(acc, off, 64);
    if (lane == 0) sdot[(size_t)(z * N_B + b) * T_S + t] = acc;
}

// ---- masked softmax over t (one block per (b,z), 512 threads) ----
__global__ void k_softmax(const float* __restrict__ sdot,
                          const int* m0, const int* m1, const int* m2,
                          float* __restrict__ attn) {
    int b = blockIdx.x, z = blockIdx.y;
    const int* mk = z == 0 ? m0 : (z == 1 ? m1 : m2);
    bool i8 = mask_is_i8(mk);
    int t = threadIdx.x;
    int base = (z * N_B + b) * T_S;
    float sval = sdot[base + t];
    if (mask_val(mk, b * T_S + t, i8) != 0) sval = -INFINITY;
    float m = sval;
#pragma unroll
    for (int off = 32; off; off >>= 1) m = fmaxf(m, __shfl_xor(m, off, 64));
    __shared__ float redm[8], reds[8];
    int w = t >> 6;
    if ((t & 63) == 0) redm[w] = m;
    __syncthreads();
    float mx = redm[0];
#pragma unroll
    for (int k = 1; k < 8; k++) mx = fmaxf(mx, redm[k]);
    float e = __expf(sval - mx);
    float ssum = e;
#pragma unroll
    for (int off = 32; off; off >>= 1) ssum += __shfl_xor(ssum, off, 64);
    if ((t & 63) == 0) reds[w] = ssum;
    __syncthreads();
    float tot = 0.f;
#pragma unroll
    for (int k = 0; k < 8; k++) tot += reds[k];
    attn[base + t] = e / tot;
}

// ==== FAST GEMM: bf16 A, global_load_lds staging, XOR-swizzled LDS ====
// h = x@W1 (+b1, relu, *attn, row-reduce -> r). 128x128 tile, BK=64.
// LDS unpadded [128][64] u16 (global_load_lds forces lane-contiguous layout);
// 16B chunk c of row r holds global chunk c^(r&7) -> fragment reads spread
// over all 8 chunk positions -> 2 lanes/bank = conflict-free (m136).
// Grid: flat = gidx*64 + xt*8 + low3; the 8 N-tiles sharing an A-row-tile
// are spaced 8 apart within 64 ids -> same XCD, temporally adjacent.
__global__ __launch_bounds__(256, 3)
void k_gemm_bf16(const u16* __restrict__ xb, const u16* __restrict__ W1T,
                 const float* __restrict__ b1, const float* __restrict__ attn,
                 float* __restrict__ r) {
    int flat = blockIdx.x;
    int low3 = flat & 7, xt = (flat >> 3) & 7;
    int g = ((flat >> 6) << 3) + low3;        // 0..383
    int z = g >> 7, yt = g & 127;
    int row0 = yt * 128, N0 = xt * 128;
    int b = row0 >> 9;

    __shared__ __align__(16) u16 As[128 * 64];
    __shared__ __align__(16) u16 Bs[128 * 64];
    __shared__ float sAttn[128];
    int tid = threadIdx.x;
    if (tid < 128) sAttn[tid] = attn[(size_t)(z * N_B + b) * T_S + (row0 & 511) + tid];

    int wave = tid >> 6, lane = tid & 63;
    int wy = wave >> 1, wx = wave & 1;
    int q = lane >> 4, cidx = lane & 15;
    int srow = lane >> 3;        // row within an 8-row staging group
    int cp = lane & 7;           // LDS 16B-chunk position within row

    floatx4 acc[4][4];
#pragma unroll
    for (int mi = 0; mi < 4; mi++)
#pragma unroll
        for (int ni = 0; ni < 4; ni++)
            acc[mi][ni] = (floatx4){0.f, 0.f, 0.f, 0.f};

    const u16* abase = xb + ((size_t)z * N_B * T_S + row0) * D_D;
    const u16* bbase = W1T + (size_t)N0 * D_D;

    for (int k0 = 0; k0 < 1024; k0 += 64) {
        __syncthreads();
        // A: 128 rows x 64 k bf16; 4 instrs/wave, 8 rows each
#pragma unroll
        for (int i = 0; i < 4; i++) {
            int r0 = wave * 32 + i * 8;
            int rr = r0 + srow;
            int gc = cp ^ (rr & 7);
            gll16(abase + (size_t)rr * D_D + k0 + gc * 8, &As[r0 * 64]);
        }
        // B: 128 n-rows x 64 k bf16 (pre-transposed W1)
#pragma unroll
        for (int i = 0; i < 4; i++) {
            int r0 = wave * 32 + i * 8;
            int nn = r0 + srow;
            int gc = cp ^ (nn & 7);
            gll16(bbase + (size_t)nn * D_D + k0 + gc * 8, &Bs[r0 * 64]);
        }
        __syncthreads();
#pragma unroll
        for (int ks = 0; ks < 2; ks++) {
            short8 a[4], bfr[4];
#pragma unroll
            for (int mi = 0; mi < 4; mi++) {
                int m = wy * 64 + mi * 16 + cidx;
                a[mi] = *(const short8*)&As[m * 64 + (((ks << 2) | q) ^ (m & 7)) * 8];
            }
#pragma unroll
            for (int ni = 0; ni < 4; ni++) {
                int n = wx * 64 + ni * 16 + cidx;
                bfr[ni] = *(const short8*)&Bs[n * 64 + (((ks << 2) | q) ^ (n & 7)) * 8];
            }
#pragma unroll
            for (int mi = 0; mi < 4; mi++)
#pragma unroll
                for (int ni = 0; ni < 4; ni++)
                    acc[mi][ni] = __builtin_amdgcn_mfma_f32_16x16x32_bf16(
                        a[mi], bfr[ni], acc[mi][ni], 0, 0, 0);
        }
    }

    float* rrow = r + (size_t)(z * N_B + b) * D_D;
#pragma unroll
    for (int ni = 0; ni < 4; ni++) {
        int ng = N0 + wx * 64 + ni * 16 + cidx;
        float b1v = b1[ng];
        float sum = 0.f;
#pragma unroll
        for (int mi = 0; mi < 4; mi++) {
#pragma unroll
            for (int rg = 0; rg < 4; rg++) {
                int ml = wy * 64 + mi * 16 + q * 4 + rg;
                float hv = acc[mi][ni][rg] + b1v;
                hv = fmaxf(hv, 0.f);
                sum += hv * sAttn[ml];
            }
        }
        sum += __shfl_xor(sum, 16, 64);
        sum += __shfl_xor(sum, 32, 64);
        if (lane < 16) atomicAdd(&rrow[ng], sum);
    }
}

// ==== FALLBACK GEMM (round-1, fp32 A staged via VGPRs) — used if ws too small ====
__global__ __launch_bounds__(256, 3)
void k_gemm_f32(const float* x0, const float* x1, const float* x2,
                const u16* __restrict__ W1T, const float* __restrict__ b1,
                const float* __restrict__ attn, float* __restrict__ r) {
    int z = blockIdx.z;
    const float* x = z == 0 ? x0 : (z == 1 ? x1 : x2);
    int tid = threadIdx.x;
    int row0 = blockIdx.y * 128;
    int N0 = blockIdx.x * 128;
    int b = row0 >> 9;

    __shared__ __align__(16) u16 As[128 * 72];
    __shared__ __align__(16) u16 Bs[128 * 72];
    __shared__ float sAttn[128];
    if (tid < 128) sAttn[tid] = attn[(size_t)(z * N_B + b) * T_S + (row0 & 511) + tid];

    int wave = tid >> 6, lane = tid & 63;
    int wy = wave >> 1, wx = wave & 1;
    int q = lane >> 4, cidx = lane & 15;

    floatx4 acc[4][4];
#pragma unroll
    for (int mi = 0; mi < 4; mi++)
#pragma unroll
        for (int ni = 0; ni < 4; ni++)
            acc[mi][ni] = (floatx4){0.f, 0.f, 0.f, 0.f};

    const float* aptr = x + (size_t)row0 * D_D;
    int acol = (tid & 15) * 4;
    int bchunk = (tid & 7) * 8;
    const u16* bptr = W1T + (size_t)N0 * D_D;

    for (int k0 = 0; k0 < 1024; k0 += 64) {
        __syncthreads();
#pragma unroll
        for (int p = 0; p < 8; p++) {
            int rr = p * 16 + (tid >> 4);
            float4 v = *(const float4*)(aptr + (size_t)rr * D_D + k0 + acol);
            union { __hip_bfloat162 h; ushort2 u; } c0, c1;
            c0.h = __float22bfloat162_rn({v.x, v.y});
            c1.h = __float22bfloat162_rn({v.z, v.w});
            ushort4 uu = {c0.u.x, c0.u.y, c1.u.x, c1.u.y};
            *(ushort4*)&As[rr * 72 + acol] = uu;
        }
#pragma unroll
        for (int p = 0; p < 4; p++) {
            int nn = p * 32 + (tid >> 3);
            short8 wv = *(const short8*)(bptr + (size_t)nn * D_D + k0 + bchunk);
            *(short8*)&Bs[nn * 72 + bchunk] = wv;
        }
        __syncthreads();
#pragma unroll
        for (int ks = 0; ks < 2; ks++) {
            short8 a[4], bf[4];
#pragma unroll
            for (int mi = 0; mi < 4; mi++) {
                int m = wy * 64 + mi * 16 + cidx;
                a[mi] = *(const short8*)&As[m * 72 + ks * 32 + q * 8];
            }
#pragma unroll
            for (int ni = 0; ni < 4; ni++) {
                int n = wx * 64 + ni * 16 + cidx;
                bf[ni] = *(const short8*)&Bs[n * 72 + ks * 32 + q * 8];
            }
#pragma unroll
            for (int mi = 0; mi < 4; mi++)
#pragma unroll
                for (int ni = 0; ni < 4; ni++)
                    acc[mi][ni] = __builtin_amdgcn_mfma_f32_16x16x32_bf16(
                        a[mi], bf[ni], acc[mi][ni], 0, 0, 0);
        }
    }

    float* rrow = r + (size_t)(z * N_B + b) * D_D;
#pragma unroll
    for (int ni = 0; ni < 4; ni++) {
        int ng = N0 + wx * 64 + ni * 16 + cidx;
        float b1v = b1[ng];
        float sum = 0.f;
#pragma unroll
        for (int mi = 0; mi < 4; mi++) {
#pragma unroll
            for (int rg = 0; rg < 4; rg++) {
                int ml = wy * 64 + mi * 16 + q * 4 + rg;
                float hv = acc[mi][ni][rg] + b1v;
                hv = fmaxf(hv, 0.f);
                sum += hv * sAttn[ml];
            }
        }
        sum += __shfl_xor(sum, 16, 64);
        sum += __shfl_xor(sum, 32, 64);
        if (lane < 16) atomicAdd(&rrow[ng], sum);
    }
}

// ---- LayerNorm + relu + (1024x120) classifier, 256 threads, split-K ----
__global__ void k_out(const float* __restrict__ pooled, const float* __restrict__ ln_g,
                      const float* __restrict__ ln_b, const float* __restrict__ Wl,
                      const float* __restrict__ bl, float* __restrict__ out) {
    int b = blockIdx.x, z = blockIdx.y;
    int tid = threadIdx.x;  // 256
    const float* p = pooled + (size_t)(z * N_B + b) * D_D;
    __shared__ float nr[D_D];
    __shared__ float redA[4], redB[4];
    __shared__ float ps[C_C];
    float vals[4];
    float s1 = 0.f, s2 = 0.f;
#pragma unroll
    for (int i = 0; i < 4; i++) {
        float v = p[i * 256 + tid];
        vals[i] = v; s1 += v; s2 += v * v;
    }
#pragma unroll
    for (int off = 32; off; off >>= 1) {
        s1 += __shfl_xor(s1, off, 64);
        s2 += __shfl_xor(s2, off, 64);
    }
    int w = tid >> 6;
    if ((tid & 63) == 0) { redA[w] = s1; redB[w] = s2; }
    __syncthreads();
    float t1 = redA[0] + redA[1] + redA[2] + redA[3];
    float t2 = redB[0] + redB[1] + redB[2] + redB[3];
    float mu = t1 * (1.0f / D_D);
    float var = t2 * (1.0f / D_D) - mu * mu;
    float rstd = 1.0f / sqrtf(var + 1e-12f);
#pragma unroll
    for (int i = 0; i < 4; i++) {
        int d = i * 256 + tid;
        float nv = (vals[i] - mu) * rstd * ln_g[d] + ln_b[d];
        nr[d] = fmaxf(nv, 0.f);
    }
    __syncthreads();
    float acc = 0.f;
    int half = tid / C_C, c = tid % C_C;
    if (tid < 2 * C_C) {
        const float* wp = Wl + (size_t)(half * 512) * C_C + c;
        const float* np = nr + half * 512;
#pragma unroll 8
        for (int d = 0; d < 512; d++)
            acc += np[d] * wp[(size_t)d * C_C];
        if (half == 1) ps[c] = acc;
    }
    __syncthreads();
    if (tid < C_C)
        out[(size_t)(z * N_B + b) * C_C + tid] = bl[tid] + acc + ps[tid];
}

extern "C" void kernel_launch(void* const* d_in, const int* in_sizes, int n_in,
                              void* d_out, int out_size, void* d_ws, size_t ws_size,
                              hipStream_t stream) {
    const float* x0 = (const float*)d_in[0];
    const float* x1 = (const float*)d_in[1];
    const float* x2 = (const float*)d_in[2];
    const int* m0 = (const int*)d_in[3];
    const int* m1 = (const int*)d_in[4];
    const int* m2 = (const int*)d_in[5];
    const float* W_attn = (const float*)d_in[6];
    const float* b_attn = (const float*)d_in[7];
    const float* W1 = (const float*)d_in[8];
    const float* b1 = (const float*)d_in[9];
    const float* W2 = (const float*)d_in[10];
    const float* b2 = (const float*)d_in[11];
    const float* ln_g = (const float*)d_in[12];
    const float* ln_b = (const float*)d_in[13];
    const float* W_last = (const float*)d_in[14];
    const float* b_last = (const float*)d_in[15];
    float* out = (float*)d_out;

    char* wsb = (char*)d_ws;
    const size_t MB = 1 << 20;
    float* WT     = (float*)(wsb);                    // 4 MB
    u16*   W1T    = (u16*)  (wsb + 4 * MB);           // 2 MB
    // zeroed region: 6MB..8MB
    float* xsum   = (float*)(wsb + 6 * MB);           // 384 KB
    float* rbuf   = (float*)(wsb + 6 * MB + 393216);  // 384 KB
    float* wsum   = (float*)(wsb + 6 * MB + 786432);  // 384 KB
    float* vs     = (float*)(wsb + 6 * MB + 1179648); // 384 KB
    float* pooled = (float*)(wsb + 6 * MB + 1572864); // 384 KB
    int*   nvalid = (int*)  (wsb + 6 * MB + 1966080); // 384 B
    // non-zeroed
    float* sdot   = (float*)(wsb + 8 * MB);           // 192 KB
    float* attn   = (float*)(wsb + 8 * MB + 196608);  // 192 KB
    u16*   x_bf16 = (u16*)  (wsb + 9 * MB);           // 96 MB (fast path)

    const size_t need_fast = 9 * MB + (size_t)3 * N_B * T_S * D_D * sizeof(u16);
    const bool fast = ws_size >= need_fast;

    hipMemsetAsync(wsb + 6 * MB, 0, 2 * MB, stream);

    k_tr_f32 <<<dim3(32, 32), dim3(32, 8), 0, stream>>>(W_attn, WT);
    k_tr_bf16<<<dim3(32, 32), dim3(32, 8), 0, stream>>>(W1, W1T);
    k_xsum   <<<dim3(8, 32, 3), 256, 0, stream>>>(x0, x1, x2, m0, m1, m2, xsum, nvalid,
                                                  fast ? x_bf16 : (u16*)nullptr);
    // wsum = xsum@W_attn + nvalid*b_attn
    k_matvec <<<dim3(16, 8, 3), 256, 0, stream>>>(W_attn, xsum, b_attn, nvalid, 1.0f, wsum);
    // vs = (W_attn . wsum)/SCALE  via transposed weights
    k_matvec <<<dim3(16, 8, 3), 256, 0, stream>>>(WT, wsum, nullptr, nullptr, 1.0f / SCALE, vs);
    k_dots   <<<dim3(128, 32, 3), 256, 0, stream>>>(x0, x1, x2, vs, sdot);
    k_softmax<<<dim3(32, 3), 512, 0, stream>>>(sdot, m0, m1, m2, attn);
    if (fast)
        k_gemm_bf16<<<3072, 256, 0, stream>>>(x_bf16, W1T, b1, attn, rbuf);
    else
        k_gemm_f32 <<<dim3(8, 128, 3), 256, 0, stream>>>(x0, x1, x2, W1T, b1, attn, rbuf);
    // pooled = r@W2 + b2
    k_matvec <<<dim3(16, 8, 3), 256, 0, stream>>>(W2, rbuf, b2, nullptr, 1.0f, pooled);
    k_out    <<<dim3(32, 3), 256, 0, stream>>>(pooled, ln_g, ln_b, W_last, b_last, out);
}